// Round 1
// 224.466 us; speedup vs baseline: 1.0415x; 1.0415x over previous
//
#include <hip/hip_runtime.h>
#include <hip/hip_bf16.h>
#include <math.h>

#define Bq 64
#define Tq 2048
#define Eq 256
#define Dq 256
#define Iq 256

using short8  = __attribute__((ext_vector_type(8))) short;
using floatx4 = __attribute__((ext_vector_type(4))) float;

__device__ __forceinline__ float fast_tanh(float x) {
    float e = __expf(2.0f * x);
    return 1.0f - 2.0f / (e + 1.0f);
}

__device__ __forceinline__ ushort f2bf(float x) {
    union { __hip_bfloat16 h; ushort u; } c;
    c.h = __float2bfloat16(x);
    return c.u;
}

// Fused prep:
//  blocks 0..31 : w1 fp32 -> bf16 fragment-ordered: w1sw[kc][i][8], kc=k/8
//  blocks 32..95: dec_proj[b][i] = sum_d dec[b][d]*w2[i][d], b=blockIdx-32
__global__ __launch_bounds__(256) void prep_kernel(
    const float* __restrict__ w1, ushort* __restrict__ w1sw,
    const float* __restrict__ dec, const float* __restrict__ w2,
    float* __restrict__ dproj)
{
    if (blockIdx.x < 32) {
        const int kc = blockIdx.x;
        const int i  = threadIdx.x;
        const float* src = w1 + i * Eq + kc * 8;
        float4 f0 = *(const float4*)src;
        float4 f1 = *(const float4*)(src + 4);
        ushort u[8] = { f2bf(f0.x), f2bf(f0.y), f2bf(f0.z), f2bf(f0.w),
                        f2bf(f1.x), f2bf(f1.y), f2bf(f1.z), f2bf(f1.w) };
        *(short8*)&w1sw[(kc * 256 + i) * 8] = *(short8*)u;
    } else {
        const int b = blockIdx.x - 32;
        const int i = threadIdx.x;
        __shared__ float dls[Dq];
        dls[i] = dec[b * Dq + i];
        __syncthreads();
        const float* w2r = w2 + i * Dq;
        float acc = 0.f;
        #pragma unroll 8
        for (int d = 0; d < Dq; ++d) acc += dls[d] * w2r[d];
        dproj[b * Iq + i] = acc;
    }
}

// Fused scores + unnormalized-context.
// K-loop restructure vs previous version:
//  - B (w1sw) is L2-resident for every block -> load fragments global->reg
//    directly (coalesced 256B segments); Bs LDS staging removed entirely.
//  - As double-buffered (2 x 9.2 KB); ONE barrier per K-step.
//  - issue order per step: B loads (L2) -> next-A loads (HBM) -> MFMA(cur)
//    -> cvt+ds_write(next) -> barrier.  In-order vmcnt retirement means the
//    MFMA's B-wait (vmcnt(4)) does NOT drain the in-flight HBM loads.
__global__ __launch_bounds__(256) void scores_ctx_kernel(
    const float*  __restrict__ enc,    // [B][T][E] fp32
    const ushort* __restrict__ w1sw,   // fragment-ordered bf16 [32 kc][256 i][8]
    const float*  __restrict__ v,      // [I]
    const float*  __restrict__ dproj,  // [B][I]
    float* __restrict__ escore,        // [B][T] unnormalized exp (probs buffer)
    float* __restrict__ ctxp,          // [32][B][E] context partials
    float* __restrict__ denomp)        // [32][B]
{
    const int b   = blockIdx.y;
    const int bx  = blockIdx.x;
    const int t0  = bx * 64;
    const int tid = threadIdx.x;
    const int w   = tid >> 6;
    const int l   = tid & 63;
    const int l15 = l & 15;
    const int lq  = l >> 4;

    __shared__ alignas(16) ushort As[2][64 * 72];  // 18.4 KB double-buffered A
    __shared__ float vls[Iq], dls[Iq];
    __shared__ float pv[64];
    __shared__ float swred[4 * 64];                // 1 KB score reduce

    vls[tid] = v[tid];
    dls[tid] = dproj[b * Iq + tid];

    floatx4 acc[4][4];
    #pragma unroll
    for (int mi = 0; mi < 4; ++mi)
        #pragma unroll
        for (int ni = 0; ni < 4; ++ni)
            acc[mi][ni] = (floatx4)0.f;

    const float* encB = enc + ((size_t)b * Tq + t0) * Eq;

    const int srow = tid >> 4;          // stage row base (+16*r)
    const int sc4  = (tid & 15) * 4;    // stage col (floats)

    // prologue: stage k0=0 tile into As[0]
    {
        float4 st[4];
        #pragma unroll
        for (int r = 0; r < 4; ++r)
            st[r] = *(const float4*)&encB[(srow + 16 * r) * Eq + sc4];
        #pragma unroll
        for (int r = 0; r < 4; ++r) {
            ushort4 u;
            u.x = f2bf(st[r].x); u.y = f2bf(st[r].y);
            u.z = f2bf(st[r].z); u.w = f2bf(st[r].w);
            *(ushort4*)&As[0][(srow + 16 * r) * 72 + sc4] = u;
        }
    }
    __syncthreads();

    const ushort* w1b = w1sw + (w * 64 + l15) * 8;  // per-lane fragment base

    #pragma unroll
    for (int k0i = 0; k0i < 4; ++k0i) {
        const int cur = k0i & 1;

        // 1. B-fragments for this K-step (L2-hot), issued FIRST
        short8 bfv[2][4];
        #pragma unroll
        for (int ks = 0; ks < 2; ++ks) {
            const int kc = k0i * 8 + ks * 4 + lq;
            #pragma unroll
            for (int ni = 0; ni < 4; ++ni)
                bfv[ks][ni] = *(const short8*)&w1b[((size_t)kc * 256 + ni * 16) * 8];
        }

        // 2. next A tile (HBM) -> regs; in flight across the MFMA section
        float4 st[4];
        if (k0i < 3) {
            #pragma unroll
            for (int r = 0; r < 4; ++r)
                st[r] = *(const float4*)&encB[(srow + 16 * r) * Eq + (k0i * 64 + 64) + sc4];
        }

        // 3. MFMA on current buffer
        __builtin_amdgcn_s_setprio(1);
        #pragma unroll
        for (int ks = 0; ks < 2; ++ks) {
            const int kloc = ks * 32 + lq * 8;
            short8 af[4];
            #pragma unroll
            for (int mi = 0; mi < 4; ++mi)
                af[mi] = *(const short8*)&As[cur][(mi * 16 + l15) * 72 + kloc];
            #pragma unroll
            for (int mi = 0; mi < 4; ++mi)
                #pragma unroll
                for (int ni = 0; ni < 4; ++ni)
                    acc[mi][ni] = __builtin_amdgcn_mfma_f32_16x16x32_bf16(
                        af[mi], bfv[ks][ni], acc[mi][ni], 0, 0, 0);
        }
        __builtin_amdgcn_s_setprio(0);

        // 4. cvt + write next A tile into the other buffer; one barrier/step
        if (k0i < 3) {
            #pragma unroll
            for (int r = 0; r < 4; ++r) {
                ushort4 u;
                u.x = f2bf(st[r].x); u.y = f2bf(st[r].y);
                u.z = f2bf(st[r].z); u.w = f2bf(st[r].w);
                *(ushort4*)&As[cur ^ 1][(srow + 16 * r) * 72 + sc4] = u;
            }
            __syncthreads();
        }
    }

    // epilogue: tanh + v-weight. C layout: col(i)=l15, row(t)=lq*4+reg.
    float part[4][4];
    #pragma unroll
    for (int mi = 0; mi < 4; ++mi)
        #pragma unroll
        for (int r = 0; r < 4; ++r) part[mi][r] = 0.f;

    #pragma unroll
    for (int ni = 0; ni < 4; ++ni) {
        const int i    = w * 64 + ni * 16 + l15;
        const float vi = vls[i];
        const float dp = dls[i];
        #pragma unroll
        for (int mi = 0; mi < 4; ++mi)
            #pragma unroll
            for (int r = 0; r < 4; ++r)
                part[mi][r] += vi * fast_tanh(acc[mi][ni][r] + dp);
    }

    // reduce over i: 4-step butterfly within the 16-lane l15 group (in-reg),
    // then 1 KB LDS for the cross-wave sum.
    #pragma unroll
    for (int mi = 0; mi < 4; ++mi)
        #pragma unroll
        for (int r = 0; r < 4; ++r) {
            float x = part[mi][r];
            x += __shfl_xor(x, 1); x += __shfl_xor(x, 2);
            x += __shfl_xor(x, 4); x += __shfl_xor(x, 8);
            part[mi][r] = x;
        }
    if (l15 == 0) {
        #pragma unroll
        for (int mi = 0; mi < 4; ++mi)
            #pragma unroll
            for (int r = 0; r < 4; ++r)
                swred[w * 64 + mi * 16 + lq * 4 + r] = part[mi][r];
    }
    __syncthreads();

    if (tid < 64) {
        float s = swred[tid] + swred[64 + tid] + swred[128 + tid] + swred[192 + tid];
        const float es = __expf(s);   // |s| <= ~16 -> safe in fp32 w/o max-sub
        pv[tid] = es;
        escore[(size_t)b * Tq + t0 + tid] = es;
        float tot = es;
        tot += __shfl_xor(tot, 1);  tot += __shfl_xor(tot, 2);
        tot += __shfl_xor(tot, 4);  tot += __shfl_xor(tot, 8);
        tot += __shfl_xor(tot, 16); tot += __shfl_xor(tot, 32);
        if (tid == 0) denomp[bx * Bq + b] = tot;
    }
    __syncthreads();

    // fused context partial: ctxp[bx][b][e] = sum_t pv[t]*enc[t][e]
    // enc tile (64 KB) was just read -> L2-resident re-read.
    const int tg = tid >> 6;            // t quarter 0..3
    const int el = (tid & 63) * 4;      // e in float4 units
    float4 a = {0.f, 0.f, 0.f, 0.f};
    #pragma unroll 8
    for (int tt = 0; tt < 16; ++tt) {
        const int t = tg * 16 + tt;     // wave-uniform
        const float pt = pv[t];
        float4 ev = *(const float4*)&encB[t * Eq + el];
        a.x += pt * ev.x; a.y += pt * ev.y; a.z += pt * ev.z; a.w += pt * ev.w;
    }
    float* redf = (float*)&As[0][0];    // 4 KB, As no longer needed
    *(float4*)&redf[tg * 256 + el] = a;
    __syncthreads();
    if (tg == 0) {
        float4 a0 = *(const float4*)&redf[0 * 256 + el];
        float4 a1 = *(const float4*)&redf[1 * 256 + el];
        float4 a2 = *(const float4*)&redf[2 * 256 + el];
        float4 a3 = *(const float4*)&redf[3 * 256 + el];
        float4 o;
        o.x = a0.x + a1.x + a2.x + a3.x;
        o.y = a0.y + a1.y + a2.y + a3.y;
        o.z = a0.z + a1.z + a2.z + a3.z;
        o.w = a0.w + a1.w + a2.w + a3.w;
        *(float4*)&ctxp[((size_t)bx * Bq + b) * Eq + el] = o;
    }
}

// One block per b: denom = sum_c denomp[c][b]; probs *= 1/denom (in place);
// ctx[b][e] = (sum_c ctxp[c][b][e]) / denom.
__global__ __launch_bounds__(256) void finalize_kernel(
    const float* __restrict__ ctxp, const float* __restrict__ denomp,
    float* __restrict__ probs, float* __restrict__ ctx)
{
    const int b   = blockIdx.x;
    const int tid = threadIdx.x;

    float d = denomp[(tid & 31) * Bq + b];
    d += __shfl_xor(d, 1);  d += __shfl_xor(d, 2);  d += __shfl_xor(d, 4);
    d += __shfl_xor(d, 8);  d += __shfl_xor(d, 16);
    const float inv = 1.0f / d;

    float* prow = probs + (size_t)b * Tq + tid * 8;
    float4 p0 = *(const float4*)(prow + 0);
    float4 p1 = *(const float4*)(prow + 4);
    p0.x *= inv; p0.y *= inv; p0.z *= inv; p0.w *= inv;
    p1.x *= inv; p1.y *= inv; p1.z *= inv; p1.w *= inv;
    *(float4*)(prow + 0) = p0;
    *(float4*)(prow + 4) = p1;

    float s = 0.f;
    #pragma unroll 8
    for (int c = 0; c < 32; ++c)
        s += ctxp[((size_t)c * Bq + b) * Eq + tid];
    ctx[b * Eq + tid] = s * inv;
}

extern "C" void kernel_launch(void* const* d_in, const int* in_sizes, int n_in,
                              void* d_out, int out_size, void* d_ws, size_t ws_size,
                              hipStream_t stream) {
    const float* enc = (const float*)d_in[0];  // [64][2048][256]
    const float* dec = (const float*)d_in[1];  // [64][256]
    const float* w1  = (const float*)d_in[2];  // [256][256]
    const float* w2  = (const float*)d_in[3];  // [256][256]
    const float* v   = (const float*)d_in[4];  // [1][256]

    float* out   = (float*)d_out;
    float* ctx   = out;                 // [64][256]  output 0
    float* probs = out + Bq * Eq;       // [64][2048] output 1 (escore first)

    char* ws = (char*)d_ws;
    float*  ctxp   = (float*)ws;                        // 2 MB  [32][64][256]
    float*  denomp = (float*)(ws + (32*Bq*Eq)*4);       // 8 KB  [32][64]
    float*  dproj  = (float*)(ws + (32*Bq*Eq)*4 + 32*Bq*4);          // 64 KB
    ushort* w1sw   = (ushort*)(ws + (32*Bq*Eq)*4 + 32*Bq*4 + Bq*Iq*4); // 128 KB

    // all ws buffers are fully overwritten each call -> no memsets needed
    prep_kernel<<<dim3(96), dim3(256), 0, stream>>>(w1, w1sw, dec, w2, dproj);
    scores_ctx_kernel<<<dim3(Tq / 64, Bq), dim3(256), 0, stream>>>(
        enc, w1sw, v, dproj, probs, ctxp, denomp);
    finalize_kernel<<<dim3(Bq), dim3(256), 0, stream>>>(ctxp, denomp, probs, ctx);
}